// Round 1
// baseline (129.466 us; speedup 1.0000x reference)
//
#include <hip/hip_runtime.h>
#include <hip/hip_bf16.h>

#define ALPHA 0.2f
#define NROW 8192

typedef __attribute__((ext_vector_type(4))) float f4;
typedef __attribute__((ext_vector_type(8))) short s8;

__device__ __forceinline__ short f2bf_bits(float x){
    __hip_bfloat16 b = __float2bfloat16(x);
    return __builtin_bit_cast(short, b);
}

// K1: h = x@W ; s1 = h@a1 ; s2 = h@a2 ; hT[f][i] = bf16(h[i][f])
__global__ __launch_bounds__(256) void k_proj(
    const float* __restrict__ x, const float* __restrict__ W, const float* __restrict__ a,
    float* __restrict__ s1, float* __restrict__ s2, __hip_bfloat16* __restrict__ hT)
{
    __shared__ float Wsh[128*64];
    __shared__ float xsh[4*128];
    const int t = threadIdx.x;
    const int f = t & 63, ry = t >> 6;
    const int row0 = blockIdx.x * 4;
    for (int i = t; i < 128*64; i += 256) Wsh[i] = W[i];
    for (int i = t; i < 4*128; i += 256) xsh[i] = x[row0*128 + i];
    __syncthreads();
    float acc = 0.f;
    #pragma unroll
    for (int k = 0; k < 128; ++k) acc = fmaf(xsh[ry*128 + k], Wsh[k*64 + f], acc);
    float p1 = acc * a[f], p2 = acc * a[64 + f];
    #pragma unroll
    for (int m = 32; m; m >>= 1){ p1 += __shfl_xor(p1, m, 64); p2 += __shfl_xor(p2, m, 64); }
    const int row = row0 + ry;
    if (f == 0){ s1[row] = p1; s2[row] = p2; }
    hT[f * NROW + row] = __float2bfloat16(acc);
}

// K2: s2max = max(s2)
__global__ __launch_bounds__(256) void k_s2max(const float* __restrict__ s2, float* __restrict__ s2max)
{
    __shared__ float red[256];
    float m = -1e30f;
    for (int i = threadIdx.x; i < NROW; i += 256) m = fmaxf(m, s2[i]);
    red[threadIdx.x] = m; __syncthreads();
    for (int s = 128; s; s >>= 1){
        if (threadIdx.x < (unsigned)s) red[threadIdx.x] = fmaxf(red[threadIdx.x], red[threadIdx.x + s]);
        __syncthreads();
    }
    if (threadIdx.x == 0) s2max[0] = red[0];
}

// K3: single-pass masked softmax (fixed shift M_i) + PV via bf16 MFMA + ELU
__global__ __launch_bounds__(512, 4) void k_attn(
    const float* __restrict__ adj, const float* __restrict__ s1g,
    const float* __restrict__ s2g, const float* __restrict__ s2maxp,
    const __hip_bfloat16* __restrict__ hT, float* __restrict__ out)
{
    const int N = NROW;
    const int tid  = threadIdx.x;
    const int wave = tid >> 6, lane = tid & 63;
    const int lr = lane & 15;     // A-row / B-col / C-col
    const int hi = lane >> 4;     // k-group 0..3
    const int i0 = blockIdx.x * 16;
    const int row = i0 + lr;

    const float s1r = s1g[row];
    float Mr = s1r + s2maxp[0];
    Mr = fmaxf(Mr, ALPHA * Mr);   // lrelu(s1r + s2max) >= true row max

    const int jseg = wave * 1024;
    const float* adjp = adj + (long)row * N + jseg + hi*8;
    const float* s2p  = s2g + jseg + hi*8;
    const __hip_bfloat16* hp = hT + lr * N + jseg + hi*8;

    f4 acc0 = {0.f,0.f,0.f,0.f}, acc1 = {0.f,0.f,0.f,0.f};
    f4 acc2 = {0.f,0.f,0.f,0.f}, acc3 = {0.f,0.f,0.f,0.f};
    float lsum = 0.f;

    f4 adjA0, adjB0, s2A0, s2B0; s8 h00, h10, h20, h30;
    f4 adjA1, adjB1, s2A1, s2B1; s8 h01, h11, h21, h31;

#define LOADB(B, c) do { \
    const float* ap = adjp + (c)*32; \
    adjA##B = *(const f4*)(ap);      adjB##B = *(const f4*)(ap + 4); \
    const float* sp = s2p + (c)*32; \
    s2A##B = *(const f4*)(sp);       s2B##B = *(const f4*)(sp + 4); \
    const __hip_bfloat16* hq = hp + (c)*32; \
    h0##B = *(const s8*)(hq); \
    h1##B = *(const s8*)(hq + 16*NROW); \
    h2##B = *(const s8*)(hq + 32*NROW); \
    h3##B = *(const s8*)(hq + 48*NROW); \
} while(0)

#define CALC(sv, av, q) { float tv = s1r + (sv); tv = fmaxf(tv, ALPHA*tv); \
    float pe = __expf(tv - Mr); q = ((av) > 0.f) ? pe : 0.f; }

#define COMPB(B) do { \
    float q0,q1,q2,q3,q4,q5,q6,q7; \
    CALC(s2A##B[0], adjA##B[0], q0); CALC(s2A##B[1], adjA##B[1], q1); \
    CALC(s2A##B[2], adjA##B[2], q2); CALC(s2A##B[3], adjA##B[3], q3); \
    CALC(s2B##B[0], adjB##B[0], q4); CALC(s2B##B[1], adjB##B[1], q5); \
    CALC(s2B##B[2], adjB##B[2], q6); CALC(s2B##B[3], adjB##B[3], q7); \
    lsum += ((q0+q1)+(q2+q3)) + ((q4+q5)+(q6+q7)); \
    s8 af; \
    af[0]=f2bf_bits(q0); af[1]=f2bf_bits(q1); af[2]=f2bf_bits(q2); af[3]=f2bf_bits(q3); \
    af[4]=f2bf_bits(q4); af[5]=f2bf_bits(q5); af[6]=f2bf_bits(q6); af[7]=f2bf_bits(q7); \
    acc0 = __builtin_amdgcn_mfma_f32_16x16x32_bf16(af, h0##B, acc0, 0, 0, 0); \
    acc1 = __builtin_amdgcn_mfma_f32_16x16x32_bf16(af, h1##B, acc1, 0, 0, 0); \
    acc2 = __builtin_amdgcn_mfma_f32_16x16x32_bf16(af, h2##B, acc2, 0, 0, 0); \
    acc3 = __builtin_amdgcn_mfma_f32_16x16x32_bf16(af, h3##B, acc3, 0, 0, 0); \
} while(0)

    LOADB(0, 0);
    for (int c = 0; c < 30; c += 2){
        LOADB(1, c+1);
        COMPB(0);
        LOADB(0, c+2);
        COMPB(1);
    }
    LOADB(1, 31);
    COMPB(0);
    COMPB(1);

#undef LOADB
#undef CALC
#undef COMPB

    // per-row denominator: reduce over the 4 k-group lanes holding row lr
    lsum += __shfl_xor(lsum, 16, 64);
    lsum += __shfl_xor(lsum, 32, 64);

    __shared__ float accb[8][16][64];   // 32 KB
    __shared__ float lsb[8][16];

    // C layout: col = lane&15, row = (lane>>4)*4 + reg
    #pragma unroll
    for (int r = 0; r < 4; ++r){
        accb[wave][hi*4 + r][ 0 + lr] = acc0[r];
        accb[wave][hi*4 + r][16 + lr] = acc1[r];
        accb[wave][hi*4 + r][32 + lr] = acc2[r];
        accb[wave][hi*4 + r][48 + lr] = acc3[r];
    }
    if (lane < 16) lsb[wave][lane] = lsum;
    __syncthreads();

    for (int idx = tid; idx < 16*64; idx += 512){
        int r = idx >> 6, cf = idx & 63;
        float s = 0.f, L = 0.f;
        #pragma unroll
        for (int w = 0; w < 8; ++w){ s += accb[w][r][cf]; L += lsb[w][r]; }
        float v = s / L;
        out[(long)(i0 + r)*64 + cf] = (v > 0.f) ? v : expm1f(v);
    }
}

extern "C" void kernel_launch(void* const* d_in, const int* in_sizes, int n_in,
                              void* d_out, int out_size, void* d_ws, size_t ws_size,
                              hipStream_t stream)
{
    const float* x   = (const float*)d_in[0];
    const float* adj = (const float*)d_in[1];
    const float* W   = (const float*)d_in[2];
    const float* a   = (const float*)d_in[3];
    float* out = (float*)d_out;

    char* ws = (char*)d_ws;
    float* s1    = (float*)(ws);                 // 32 KB
    float* s2    = (float*)(ws + 32768);         // 32 KB
    float* s2mx  = (float*)(ws + 65536);         // 4 B (padded to 256)
    __hip_bfloat16* hT = (__hip_bfloat16*)(ws + 65536 + 256);  // 1 MB

    k_proj <<<2048, 256, 0, stream>>>(x, W, a, s1, s2, hT);
    k_s2max<<<   1, 256, 0, stream>>>(s2, s2mx);
    k_attn <<< 512, 512, 0, stream>>>(adj, s1, s2, s2mx, hT, out);
}